// Round 1
// baseline (1927.224 us; speedup 1.0000x reference)
//
#include <hip/hip_runtime.h>
#include <math.h>

// Model: PINNDamageLocator
// B=8, E=36 -> N=288 samples through conv stack.
// conv1: (288,4,32,2048) -> (288,16,32,1024), bn+relu, pool -> (288,16,16,512), SE1
// conv2: -> (288,32,16,256), bn+relu, pool -> (288,32,8,128), SE2
// conv3: -> (288,64,8,64), bn+relu, mean -> (288,64)
// then edge_fc + GNN + attention heads -> (reg[8,3], cls[8,9], ea[8,36])

// ---------------- conv1 + bn1 + relu + maxpool + SE1-sum ----------------
__global__ __launch_bounds__(256) void k_conv1(
    const float* __restrict__ x, const float* __restrict__ w,
    const float* __restrict__ cb, const float* __restrict__ bs,
    const float* __restrict__ bb, const float* __restrict__ bm,
    const float* __restrict__ bv,
    float* __restrict__ h1, float* __restrict__ sesum)
{
  int bid = blockIdx.x;                  // n*32 + ph*2 + half
  int n = bid >> 5, rem = bid & 31, ph = rem >> 1, half = rem & 1;
  int pw = (half << 8) + threadIdx.x;    // 0..511
  __shared__ float wl[4][3][3][16];
  __shared__ float sc[16], bi[16];
  for (int i = threadIdx.x; i < 576; i += 256) {
    int co = i / 36, r = i % 36, ci = r / 9, kk = r % 9;
    wl[ci][kk/3][kk%3][co] = w[i];
  }
  if (threadIdx.x < 16) {
    int c = threadIdx.x;
    float s = bs[c] * rsqrtf(bv[c] + 1e-5f);
    sc[c] = s;
    bi[c] = bb[c] + (cb[c] - bm[c]) * s;
  }
  __syncthreads();
  const float* xn = x + (size_t)n * 4 * 32 * 2048;
  float pooled[16];
#pragma unroll
  for (int c = 0; c < 16; c++) pooled[c] = 0.f;   // relu output >= 0
#pragma unroll
  for (int dh = 0; dh < 2; dh++) {
    int h = 2 * ph + dh;
#pragma unroll
    for (int dw = 0; dw < 2; dw++) {
      int wp = 2 * pw + dw;                      // conv output col, 0..1023
      float acc[16];
#pragma unroll
      for (int c = 0; c < 16; c++) acc[c] = 0.f;
#pragma unroll
      for (int ci = 0; ci < 4; ci++) {
        const float* xc = xn + ci * 32 * 2048;
#pragma unroll
        for (int kh = 0; kh < 3; kh++) {
          int ih = h + kh - 1;
          if (ih < 0 || ih >= 32) continue;      // uniform per block
          const float* xr = xc + ih * 2048;
#pragma unroll
          for (int kw = 0; kw < 3; kw++) {
            int iw = 2 * wp + kw - 1;            // max 2047, only iw<0 possible OOB
            if (iw < 0) continue;
            float v = xr[iw];
#pragma unroll
            for (int co = 0; co < 16; co++)
              acc[co] = fmaf(v, wl[ci][kh][kw][co], acc[co]);
          }
        }
      }
#pragma unroll
      for (int co = 0; co < 16; co++) {
        float v = fmaxf(acc[co] * sc[co] + bi[co], 0.f);
        pooled[co] = fmaxf(pooled[co], v);
      }
    }
  }
#pragma unroll
  for (int co = 0; co < 16; co++)
    h1[(((size_t)n * 16 + co) * 16 + ph) * 512 + pw] = pooled[co];
  int lane = threadIdx.x & 63;
#pragma unroll
  for (int co = 0; co < 16; co++) {
    float v = pooled[co];
    for (int off = 32; off; off >>= 1) v += __shfl_down(v, off);
    if (lane == 0) atomicAdd(&sesum[n * 16 + co], v);
  }
}

// ---------------- SE MLP (generic): mean -> relu fc -> sigmoid fc ----------------
__global__ void k_se(const float* __restrict__ sesum, int C, int Cr, float invcnt,
                     const float* __restrict__ w1, const float* __restrict__ b1,
                     const float* __restrict__ w2, const float* __restrict__ b2,
                     float* __restrict__ s)
{
  int n = blockIdx.x * blockDim.x + threadIdx.x;
  if (n >= 288) return;
  float y[32], t[8];
  for (int c = 0; c < C; c++) y[c] = sesum[n * C + c] * invcnt;
  for (int r = 0; r < Cr; r++) {
    float a = b1[r];
    for (int c = 0; c < C; c++) a += y[c] * w1[r * C + c];
    t[r] = fmaxf(a, 0.f);
  }
  for (int c = 0; c < C; c++) {
    float a = b2[c];
    for (int r = 0; r < Cr; r++) a += t[r] * w2[c * Cr + r];
    s[n * C + c] = 1.f / (1.f + expf(-a));
  }
}

// ---------------- conv2 (input scaled by SE1) + bn2 + relu + pool + SE2-sum ----------------
__global__ __launch_bounds__(128) void k_conv2(
    const float* __restrict__ h1, const float* __restrict__ w,
    const float* __restrict__ cb, const float* __restrict__ bs,
    const float* __restrict__ bb, const float* __restrict__ bm,
    const float* __restrict__ bv,
    const float* __restrict__ s1,
    float* __restrict__ h2, float* __restrict__ sesum)
{
  int bid = blockIdx.x;                 // n*8 + ph
  int n = bid >> 3, ph = bid & 7;
  int pw = threadIdx.x;                 // 0..127
  __shared__ float wl[16][3][3][32];    // 18 KB
  __shared__ float sc[32], bi[32];
  for (int i = threadIdx.x; i < 4608; i += 128) {
    int co = i / 144, r = i % 144, ci = r / 9, kk = r % 9;
    wl[ci][kk/3][kk%3][co] = w[i];
  }
  if (threadIdx.x < 32) {
    int c = threadIdx.x;
    float s = bs[c] * rsqrtf(bv[c] + 1e-5f);
    sc[c] = s;
    bi[c] = bb[c] + (cb[c] - bm[c]) * s;
  }
  __syncthreads();
  float s1n[16];
#pragma unroll
  for (int ci = 0; ci < 16; ci++) s1n[ci] = s1[n * 16 + ci];
  const float* hn = h1 + (size_t)n * 16 * 16 * 512;
  float pooled[32];
#pragma unroll
  for (int c = 0; c < 32; c++) pooled[c] = 0.f;
#pragma unroll
  for (int dh = 0; dh < 2; dh++) {
    int h = 2 * ph + dh;
#pragma unroll
    for (int dw = 0; dw < 2; dw++) {
      int wp = 2 * pw + dw;             // 0..255
      float acc[32];
#pragma unroll
      for (int c = 0; c < 32; c++) acc[c] = 0.f;
      for (int ci = 0; ci < 16; ci++) {
        const float* hc = hn + ci * 16 * 512;
        float sf = s1n[ci];
#pragma unroll
        for (int kh = 0; kh < 3; kh++) {
          int ih = h + kh - 1;
          if (ih < 0 || ih >= 16) continue;
          const float* hr = hc + ih * 512;
#pragma unroll
          for (int kw = 0; kw < 3; kw++) {
            int iw = 2 * wp + kw - 1;   // max 511
            if (iw < 0) continue;
            float v = hr[iw] * sf;
#pragma unroll
            for (int co = 0; co < 32; co++)
              acc[co] = fmaf(v, wl[ci][kh][kw][co], acc[co]);
          }
        }
      }
#pragma unroll
      for (int co = 0; co < 32; co++) {
        float v = fmaxf(acc[co] * sc[co] + bi[co], 0.f);
        pooled[co] = fmaxf(pooled[co], v);
      }
    }
  }
#pragma unroll
  for (int co = 0; co < 32; co++)
    h2[(((size_t)n * 32 + co) * 8 + ph) * 128 + pw] = pooled[co];
  int lane = threadIdx.x & 63;
#pragma unroll
  for (int co = 0; co < 32; co++) {
    float v = pooled[co];
    for (int off = 32; off; off >>= 1) v += __shfl_down(v, off);
    if (lane == 0) atomicAdd(&sesum[n * 32 + co], v);
  }
}

// ---------------- conv3 (input scaled by SE2) + bn3 + relu + global mean ----------------
__global__ __launch_bounds__(256) void k_conv3(
    const float* __restrict__ h2, const float* __restrict__ w,
    const float* __restrict__ cb, const float* __restrict__ bs,
    const float* __restrict__ bb, const float* __restrict__ bm,
    const float* __restrict__ bv,
    const float* __restrict__ s2, float* __restrict__ h3)
{
  int bid = blockIdx.x;                 // n*4 + cog (16 out channels per cog)
  int n = bid >> 2, cog = bid & 3;
  __shared__ float wl[32][3][3][16];    // 18 KB
  __shared__ float sc[16], bi[16];
  for (int i = threadIdx.x; i < 4608; i += 256) {
    int k = i / 288, r = i % 288, ci = r / 9, kk = r % 9;
    wl[ci][kk/3][kk%3][k] = w[((cog * 16 + k) * 32 + ci) * 9 + kk];
  }
  if (threadIdx.x < 16) {
    int c = cog * 16 + threadIdx.x;
    float s = bs[c] * rsqrtf(bv[c] + 1e-5f);
    sc[threadIdx.x] = s;
    bi[threadIdx.x] = bb[c] + (cb[c] - bm[c]) * s;
  }
  __syncthreads();
  float s2n[32];
#pragma unroll
  for (int ci = 0; ci < 32; ci++) s2n[ci] = s2[n * 32 + ci];
  const float* hn = h2 + (size_t)n * 32 * 8 * 128;
  float sums[16];
#pragma unroll
  for (int k = 0; k < 16; k++) sums[k] = 0.f;
  for (int p = threadIdx.x; p < 512; p += 256) {  // 2 spatial positions/thread
    int hh = p >> 6, wp = p & 63;
    float acc[16];
#pragma unroll
    for (int k = 0; k < 16; k++) acc[k] = 0.f;
    for (int ci = 0; ci < 32; ci++) {
      const float* hc = hn + ci * 8 * 128;
      float sf = s2n[ci];
#pragma unroll
      for (int kh = 0; kh < 3; kh++) {
        int ih = hh + kh - 1;
        if (ih < 0 || ih >= 8) continue;
        const float* hr = hc + ih * 128;
#pragma unroll
        for (int kw = 0; kw < 3; kw++) {
          int iw = 2 * wp + kw - 1;     // max 127
          if (iw < 0) continue;
          float v = hr[iw] * sf;
#pragma unroll
          for (int k = 0; k < 16; k++)
            acc[k] = fmaf(v, wl[ci][kh][kw][k], acc[k]);
        }
      }
    }
#pragma unroll
    for (int k = 0; k < 16; k++)
      sums[k] += fmaxf(acc[k] * sc[k] + bi[k], 0.f);
  }
  __shared__ float red[16][4];
  int lane = threadIdx.x & 63, wv = threadIdx.x >> 6;
#pragma unroll
  for (int k = 0; k < 16; k++) {
    float v = sums[k];
    for (int off = 32; off; off >>= 1) v += __shfl_down(v, off);
    if (lane == 0) red[k][wv] = v;
  }
  __syncthreads();
  if (threadIdx.x < 16) {
    int k = threadIdx.x;
    float t = red[k][0] + red[k][1] + red[k][2] + red[k][3];
    h3[n * 64 + cog * 16 + k] = t * (1.f / 512.f);
  }
}

// ---------------- head: edge_fc + GNN scatter + e2n + attention + outputs ----------------
__global__ __launch_bounds__(256) void k_head(
    const float* __restrict__ h3,
    const float* __restrict__ efw, const float* __restrict__ efb,
    const float* __restrict__ ew,
    const float* __restrict__ e2nw, const float* __restrict__ e2nb,
    const float* __restrict__ a1w, const float* __restrict__ a1b,
    const float* __restrict__ a2w,
    const float* __restrict__ clsw, const float* __restrict__ clsb,
    const float* __restrict__ regw, const float* __restrict__ regb,
    float* __restrict__ out)
{
  int b = blockIdx.x;
  int tid = threadIdx.x;
  __shared__ float ef[36][64];      // weighted edge features
  __shared__ float nin[12][64];
  __shared__ float nd[12][128];
  __shared__ float tmp[12][64];
  __shared__ float spw[36], aw[12], scv[12], g[128], ea[36];
  if (tid < 36) {
    float xw = ew[tid];
    spw[tid] = (xw > 20.f) ? xw : log1pf(expf(xw));   // softplus
  }
  __syncthreads();
  // edge_fc: relu(h3 @ efw.T + efb) * softplus(edge_w)
  for (int idx = tid; idx < 36 * 64; idx += 256) {
    int e = idx >> 6, d = idx & 63;
    const float* hr = h3 + (size_t)(b * 36 + e) * 64;
    const float* wr = efw + d * 64;
    float a = efb[d];
    for (int k = 0; k < 64; k++) a += hr[k] * wr[k];
    ef[e][d] = fmaxf(a, 0.f) * spw[e];
  }
  __syncthreads();
  // scatter-add to 12 nodes: U[e]=e/6 (nodes 0..5), V[e]=6+e%6 (nodes 6..11)
  for (int idx = tid; idx < 12 * 64; idx += 256) {
    int j = idx >> 6, d = idx & 63;
    float a = 0.f;
    if (j < 6) { for (int i = 0; i < 6; i++) a += ef[j * 6 + i][d]; }
    else       { for (int i = 0; i < 6; i++) a += ef[i * 6 + (j - 6)][d]; }
    nin[j][d] = a;
  }
  __syncthreads();
  // e2n: relu(nin @ e2nw.T + e2nb) -> node[12][128]
  for (int idx = tid; idx < 12 * 128; idx += 256) {
    int j = idx >> 7, d = idx & 127;
    const float* wr = e2nw + d * 64;
    float a = e2nb[d];
    for (int k = 0; k < 64; k++) a += nin[j][k] * wr[k];
    nd[j][d] = fmaxf(a, 0.f);
  }
  __syncthreads();
  // attention scores: tanh(node @ a1w.T + a1b) @ a2w.T
  for (int idx = tid; idx < 12 * 64; idx += 256) {
    int j = idx >> 6, hh = idx & 63;
    const float* wr = a1w + hh * 128;
    float a = a1b[hh];
    for (int k = 0; k < 128; k++) a += nd[j][k] * wr[k];
    tmp[j][hh] = tanhf(a) * a2w[hh];
  }
  __syncthreads();
  if (tid < 12) {
    float a = 0.f;
    for (int h = 0; h < 64; h++) a += tmp[tid][h];
    scv[tid] = a;
  }
  __syncthreads();
  if (tid == 0) {
    float m = scv[0];
    for (int j = 1; j < 12; j++) m = fmaxf(m, scv[j]);
    float s = 0.f;
    for (int j = 0; j < 12; j++) { float z = expf(scv[j] - m); aw[j] = z; s += z; }
    float inv = 1.f / s;
    for (int j = 0; j < 12; j++) aw[j] *= inv;
    float rs = 0.f;
    for (int e = 0; e < 36; e++) { float r = aw[e / 6] * aw[6 + e % 6]; ea[e] = r; rs += r; }
    float inv2 = 1.f / (rs + 1e-8f);
    for (int e = 0; e < 36; e++) ea[e] *= inv2;
  }
  __syncthreads();
  if (tid < 36) out[96 + b * 36 + tid] = ea[tid];
  if (tid < 128) {
    float a = 0.f;
    for (int j = 0; j < 12; j++) a += nd[j][tid] * aw[j];
    g[tid] = a;
  }
  __syncthreads();
  if (tid < 3) {
    const float* wr = regw + tid * 128;
    float a = regb[tid];
    for (int k = 0; k < 128; k++) a += g[k] * wr[k];
    out[b * 3 + tid] = a;             // reg: [0, 24)
  }
  if (tid >= 64 && tid < 73) {
    int i = tid - 64;
    const float* wr = clsw + i * 128;
    float a = clsb[i];
    for (int k = 0; k < 128; k++) a += g[k] * wr[k];
    out[24 + b * 9 + i] = a;          // cls: [24, 96)
  }
}

extern "C" void kernel_launch(void* const* d_in, const int* in_sizes, int n_in,
                              void* d_out, int out_size, void* d_ws, size_t ws_size,
                              hipStream_t stream) {
  const float* x      = (const float*)d_in[0];
  const float* c1w    = (const float*)d_in[1];
  const float* c1b    = (const float*)d_in[2];
  const float* bn1s   = (const float*)d_in[3];
  const float* bn1b   = (const float*)d_in[4];
  const float* bn1m   = (const float*)d_in[5];
  const float* bn1v   = (const float*)d_in[6];
  const float* se1w1  = (const float*)d_in[7];
  const float* se1b1  = (const float*)d_in[8];
  const float* se1w2  = (const float*)d_in[9];
  const float* se1b2  = (const float*)d_in[10];
  const float* c2w    = (const float*)d_in[11];
  const float* c2b    = (const float*)d_in[12];
  const float* bn2s   = (const float*)d_in[13];
  const float* bn2b   = (const float*)d_in[14];
  const float* bn2m   = (const float*)d_in[15];
  const float* bn2v   = (const float*)d_in[16];
  const float* se2w1  = (const float*)d_in[17];
  const float* se2b1  = (const float*)d_in[18];
  const float* se2w2  = (const float*)d_in[19];
  const float* se2b2  = (const float*)d_in[20];
  const float* c3w    = (const float*)d_in[21];
  const float* c3b    = (const float*)d_in[22];
  const float* bn3s   = (const float*)d_in[23];
  const float* bn3b   = (const float*)d_in[24];
  const float* bn3m   = (const float*)d_in[25];
  const float* bn3v   = (const float*)d_in[26];
  const float* efw    = (const float*)d_in[27];
  const float* efb    = (const float*)d_in[28];
  const float* ew     = (const float*)d_in[29];
  const float* e2nw   = (const float*)d_in[30];
  const float* e2nb   = (const float*)d_in[31];
  const float* a1w    = (const float*)d_in[32];
  const float* a1b    = (const float*)d_in[33];
  const float* a2w    = (const float*)d_in[34];
  const float* clsw   = (const float*)d_in[35];
  const float* clsb   = (const float*)d_in[36];
  const float* regw   = (const float*)d_in[37];
  const float* regb   = (const float*)d_in[38];

  float* ws = (float*)d_ws;
  float* h1     = ws;                        // 288*16*16*512 = 37,748,736 f
  float* h2     = h1 + 37748736;             // 288*32*8*128  =  9,437,184 f
  float* sesum1 = h2 + 9437184;              // 288*16 = 4608 f
  float* s1     = sesum1 + 4608;             // 4608 f
  float* sesum2 = s1 + 4608;                 // 288*32 = 9216 f
  float* s2     = sesum2 + 9216;             // 9216 f
  float* h3     = s2 + 9216;                 // 288*64 = 18432 f
  // total: 47,232,000 floats = 188.9 MB of d_ws

  hipMemsetAsync(sesum1, 0, 4608 * sizeof(float), stream);
  hipMemsetAsync(sesum2, 0, 9216 * sizeof(float), stream);

  k_conv1<<<288 * 32, 256, 0, stream>>>(x, c1w, c1b, bn1s, bn1b, bn1m, bn1v, h1, sesum1);
  k_se<<<5, 64, 0, stream>>>(sesum1, 16, 4, 1.f / 8192.f, se1w1, se1b1, se1w2, se1b2, s1);
  k_conv2<<<288 * 8, 128, 0, stream>>>(h1, c2w, c2b, bn2s, bn2b, bn2m, bn2v, s1, h2, sesum2);
  k_se<<<5, 64, 0, stream>>>(sesum2, 32, 8, 1.f / 1024.f, se2w1, se2b1, se2w2, se2b2, s2);
  k_conv3<<<288 * 4, 256, 0, stream>>>(h2, c3w, c3b, bn3s, bn3b, bn3m, bn3v, s2, h3);
  k_head<<<8, 256, 0, stream>>>(h3, efw, efb, ew, e2nw, e2nb, a1w, a1b, a2w,
                                clsw, clsb, regw, regb, (float*)d_out);
}

// Round 2
// 1314.102 us; speedup vs baseline: 1.4666x; 1.4666x over previous
//
#include <hip/hip_runtime.h>
#include <math.h>

// Model: PINNDamageLocator
// B=8, E=36 -> N=288 samples through conv stack.
// conv1: (288,4,32,2048) -> bn+relu -> pool -> (288,16,16,512), SE1
// conv2: -> bn+relu -> pool -> (288,32,8,128), SE2
// conv3: -> bn+relu -> mean -> (288,64)
// then edge_fc + GNN + attention heads -> (reg[8,3], cls[8,9], ea[8,36])
//
// Design: each thread owns ONE pooled output column and 16 (or 32) output
// channels in register accumulators. Input strips loaded as aligned float4 +
// 1 scalar (5-col halo). BN scale (and SE input scale for conv2/3) folded
// into the LDS weight copy at load time; BN shift + conv bias folded into a
// per-channel bias. So the inner loop is pure load+FMA.

// ---------------- conv1 + bn1 + relu + maxpool + SE1-sum ----------------
__global__ __launch_bounds__(256) void k_conv1(
    const float* __restrict__ x, const float* __restrict__ w,
    const float* __restrict__ cb, const float* __restrict__ bs,
    const float* __restrict__ bb, const float* __restrict__ bm,
    const float* __restrict__ bv,
    float* __restrict__ h1, float* __restrict__ sesum)
{
  int bid = blockIdx.x;                  // n*32 + ph*2 + half
  int n = bid >> 5, rem = bid & 31, ph = rem >> 1, half = rem & 1;
  int pw = (half << 8) + threadIdx.x;    // pooled col 0..511
  __shared__ float wl[4][3][3][16];      // [ci][kh][kw][co], bn-scale folded
  __shared__ float bi[16];
  for (int i = threadIdx.x; i < 576; i += 256) {
    int co = i / 36, r = i % 36, ci = r / 9, kk = r % 9;
    float s = bs[co] * rsqrtf(bv[co] + 1e-5f);
    wl[ci][kk / 3][kk % 3][co] = w[i] * s;
  }
  if (threadIdx.x < 16) {
    int c = threadIdx.x;
    float s = bs[c] * rsqrtf(bv[c] + 1e-5f);
    bi[c] = bb[c] + (cb[c] - bm[c]) * s;
  }
  __syncthreads();
  const float* xn = x + (size_t)n * 4 * 32 * 2048;
  float pooled[16];
#pragma unroll
  for (int c = 0; c < 16; c++) pooled[c] = 0.f;   // relu output >= 0
#pragma unroll
  for (int dh = 0; dh < 2; dh++) {
    float acc[2][16];
#pragma unroll
    for (int cc = 0; cc < 2; cc++)
#pragma unroll
      for (int c = 0; c < 16; c++) acc[cc][c] = 0.f;
#pragma unroll
    for (int ci = 0; ci < 4; ci++) {
#pragma unroll
      for (int kh = 0; kh < 3; kh++) {
        int ih = 2 * ph + dh + kh - 1;
        if (ih < 0 || ih >= 32) continue;          // block-uniform
        const float* xr = xn + (ci * 32 + ih) * 2048;
        float4 v4 = *reinterpret_cast<const float4*>(xr + 4 * pw);
        float in0 = pw ? xr[4 * pw - 1] : 0.f;
        float strip[5] = {in0, v4.x, v4.y, v4.z, v4.w};
#pragma unroll
        for (int cc = 0; cc < 2; cc++) {
#pragma unroll
          for (int kw = 0; kw < 3; kw++) {
            float v = strip[2 * cc + kw];
#pragma unroll
            for (int co = 0; co < 16; co++)
              acc[cc][co] = fmaf(v, wl[ci][kh][kw][co], acc[cc][co]);
          }
        }
      }
    }
#pragma unroll
    for (int co = 0; co < 16; co++) {
      float a = fmaxf(acc[0][co] + bi[co], 0.f);
      float b = fmaxf(acc[1][co] + bi[co], 0.f);
      pooled[co] = fmaxf(pooled[co], fmaxf(a, b));
    }
  }
#pragma unroll
  for (int co = 0; co < 16; co++)
    h1[(((size_t)n * 16 + co) * 16 + ph) * 512 + pw] = pooled[co];
  int lane = threadIdx.x & 63;
#pragma unroll
  for (int co = 0; co < 16; co++) {
    float v = pooled[co];
    for (int off = 32; off; off >>= 1) v += __shfl_down(v, off);
    if (lane == 0) atomicAdd(&sesum[n * 16 + co], v);
  }
}

// ---------------- SE MLP (generic): mean -> relu fc -> sigmoid fc ----------------
__global__ void k_se(const float* __restrict__ sesum, int C, int Cr, float invcnt,
                     const float* __restrict__ w1, const float* __restrict__ b1,
                     const float* __restrict__ w2, const float* __restrict__ b2,
                     float* __restrict__ s)
{
  int n = blockIdx.x * blockDim.x + threadIdx.x;
  if (n >= 288) return;
  float y[32], t[8];
  for (int c = 0; c < C; c++) y[c] = sesum[n * C + c] * invcnt;
  for (int r = 0; r < Cr; r++) {
    float a = b1[r];
    for (int c = 0; c < C; c++) a += y[c] * w1[r * C + c];
    t[r] = fmaxf(a, 0.f);
  }
  for (int c = 0; c < C; c++) {
    float a = b2[c];
    for (int r = 0; r < Cr; r++) a += t[r] * w2[c * Cr + r];
    s[n * C + c] = 1.f / (1.f + expf(-a));
  }
}

// ---------------- conv2 (SE1 folded) + bn2 + relu + pool + SE2-sum ----------------
__global__ __launch_bounds__(256) void k_conv2(
    const float* __restrict__ h1, const float* __restrict__ w,
    const float* __restrict__ cb, const float* __restrict__ bs,
    const float* __restrict__ bb, const float* __restrict__ bm,
    const float* __restrict__ bv,
    const float* __restrict__ s1,
    float* __restrict__ h2, float* __restrict__ sesum)
{
  int bid = blockIdx.x;                 // n*8 + ph
  int n = bid >> 3, ph = bid & 7;
  int cog = threadIdx.x >> 7;           // 0,1 -> co range cog*16..cog*16+15
  int wp = threadIdx.x & 127;           // pooled col 0..127
  __shared__ float wl[16][3][3][32];    // bn scale * se1 scale folded
  __shared__ float bi[32];
  const float* s1n = s1 + n * 16;
  for (int i = threadIdx.x; i < 4608; i += 256) {
    int co = i / 144, r = i % 144, ci = r / 9, kk = r % 9;
    float s = bs[co] * rsqrtf(bv[co] + 1e-5f);
    wl[ci][kk / 3][kk % 3][co] = w[i] * s * s1n[ci];
  }
  if (threadIdx.x < 32) {
    int c = threadIdx.x;
    float s = bs[c] * rsqrtf(bv[c] + 1e-5f);
    bi[c] = bb[c] + (cb[c] - bm[c]) * s;
  }
  __syncthreads();
  const float* hn = h1 + (size_t)n * 16 * 16 * 512;
  float pooled[16];
#pragma unroll
  for (int c = 0; c < 16; c++) pooled[c] = 0.f;
#pragma unroll
  for (int dh = 0; dh < 2; dh++) {
    float acc[2][16];
#pragma unroll
    for (int cc = 0; cc < 2; cc++)
#pragma unroll
      for (int c = 0; c < 16; c++) acc[cc][c] = 0.f;
    for (int ci = 0; ci < 16; ci++) {
#pragma unroll
      for (int kh = 0; kh < 3; kh++) {
        int ih = 2 * ph + dh + kh - 1;
        if (ih < 0 || ih >= 16) continue;
        const float* hr = hn + (ci * 16 + ih) * 512;
        float4 v4 = *reinterpret_cast<const float4*>(hr + 4 * wp);
        float in0 = wp ? hr[4 * wp - 1] : 0.f;
        float strip[5] = {in0, v4.x, v4.y, v4.z, v4.w};
#pragma unroll
        for (int cc = 0; cc < 2; cc++) {
#pragma unroll
          for (int kw = 0; kw < 3; kw++) {
            float v = strip[2 * cc + kw];
#pragma unroll
            for (int co = 0; co < 16; co++)
              acc[cc][co] = fmaf(v, wl[ci][kh][kw][cog * 16 + co], acc[cc][co]);
          }
        }
      }
    }
#pragma unroll
    for (int co = 0; co < 16; co++) {
      float a = fmaxf(acc[0][co] + bi[cog * 16 + co], 0.f);
      float b = fmaxf(acc[1][co] + bi[cog * 16 + co], 0.f);
      pooled[co] = fmaxf(pooled[co], fmaxf(a, b));
    }
  }
#pragma unroll
  for (int co = 0; co < 16; co++)
    h2[(((size_t)n * 32 + cog * 16 + co) * 8 + ph) * 128 + wp] = pooled[co];
  int lane = threadIdx.x & 63;
#pragma unroll
  for (int co = 0; co < 16; co++) {
    float v = pooled[co];
    for (int off = 32; off; off >>= 1) v += __shfl_down(v, off);
    if (lane == 0) atomicAdd(&sesum[n * 32 + cog * 16 + co], v);
  }
}

// ---------------- conv3 (SE2 folded) + bn3 + relu + global mean ----------------
__global__ __launch_bounds__(256) void k_conv3(
    const float* __restrict__ h2, const float* __restrict__ w,
    const float* __restrict__ cb, const float* __restrict__ bs,
    const float* __restrict__ bb, const float* __restrict__ bm,
    const float* __restrict__ bv,
    const float* __restrict__ s2, float* __restrict__ h3)
{
  int bid = blockIdx.x;                 // n*2 + cog (32 out channels per cog)
  int n = bid >> 1, cog = bid & 1;
  __shared__ float wl[32][3][3][32];    // [ci][kh][kw][k], 36 KB, scales folded
  __shared__ float bi[32];
  __shared__ float red[4][32];
  const float* s2n = s2 + n * 32;
  for (int i = threadIdx.x; i < 9216; i += 256) {
    int k = i / 288, r = i % 288, ci = r / 9, kk = r % 9;
    int co = cog * 32 + k;
    float s = bs[co] * rsqrtf(bv[co] + 1e-5f);
    wl[ci][kk / 3][kk % 3][k] = w[(size_t)co * 288 + r] * s * s2n[ci];
  }
  if (threadIdx.x < 32) {
    int c = cog * 32 + threadIdx.x;
    float s = bs[c] * rsqrtf(bv[c] + 1e-5f);
    bi[threadIdx.x] = bb[c] + (cb[c] - bm[c]) * s;
  }
  __syncthreads();
  const float* hn = h2 + (size_t)n * 32 * 8 * 128;
  float sums[32];
#pragma unroll
  for (int k = 0; k < 32; k++) sums[k] = 0.f;
  for (int p = threadIdx.x; p < 512; p += 256) {  // 2 positions/thread, wave-uniform hh
    int hh = p >> 6, wp = p & 63;
    float acc[32];
#pragma unroll
    for (int k = 0; k < 32; k++) acc[k] = 0.f;
    for (int ci = 0; ci < 32; ci++) {
#pragma unroll
      for (int kh = 0; kh < 3; kh++) {
        int ih = hh + kh - 1;
        if (ih < 0 || ih >= 8) continue;
        const float* hr = hn + (ci * 8 + ih) * 128;
        float2 v2 = *reinterpret_cast<const float2*>(hr + 2 * wp);
        float in0 = wp ? hr[2 * wp - 1] : 0.f;
        float strip[3] = {in0, v2.x, v2.y};
#pragma unroll
        for (int kw = 0; kw < 3; kw++) {
          float v = strip[kw];
#pragma unroll
          for (int k = 0; k < 32; k++)
            acc[k] = fmaf(v, wl[ci][kh][kw][k], acc[k]);
        }
      }
    }
#pragma unroll
    for (int k = 0; k < 32; k++)
      sums[k] += fmaxf(acc[k] + bi[k], 0.f);
  }
  int lane = threadIdx.x & 63, wv = threadIdx.x >> 6;
#pragma unroll
  for (int k = 0; k < 32; k++) {
    float v = sums[k];
    for (int off = 32; off; off >>= 1) v += __shfl_down(v, off);
    if (lane == 0) red[wv][k] = v;
  }
  __syncthreads();
  if (threadIdx.x < 32) {
    int k = threadIdx.x;
    float t = red[0][k] + red[1][k] + red[2][k] + red[3][k];
    h3[n * 64 + cog * 32 + k] = t * (1.f / 512.f);
  }
}

// ---------------- head: edge_fc + GNN scatter + e2n + attention + outputs ----------------
__global__ __launch_bounds__(256) void k_head(
    const float* __restrict__ h3,
    const float* __restrict__ efw, const float* __restrict__ efb,
    const float* __restrict__ ew,
    const float* __restrict__ e2nw, const float* __restrict__ e2nb,
    const float* __restrict__ a1w, const float* __restrict__ a1b,
    const float* __restrict__ a2w,
    const float* __restrict__ clsw, const float* __restrict__ clsb,
    const float* __restrict__ regw, const float* __restrict__ regb,
    float* __restrict__ out)
{
  int b = blockIdx.x;
  int tid = threadIdx.x;
  __shared__ float ef[36][64];      // weighted edge features
  __shared__ float nin[12][64];
  __shared__ float nd[12][128];
  __shared__ float tmp[12][64];
  __shared__ float spw[36], aw[12], scv[12], g[128], ea[36];
  if (tid < 36) {
    float xw = ew[tid];
    spw[tid] = (xw > 20.f) ? xw : log1pf(expf(xw));   // softplus
  }
  __syncthreads();
  // edge_fc: relu(h3 @ efw.T + efb) * softplus(edge_w)
  for (int idx = tid; idx < 36 * 64; idx += 256) {
    int e = idx >> 6, d = idx & 63;
    const float* hr = h3 + (size_t)(b * 36 + e) * 64;
    const float* wr = efw + d * 64;
    float a = efb[d];
    for (int k = 0; k < 64; k++) a += hr[k] * wr[k];
    ef[e][d] = fmaxf(a, 0.f) * spw[e];
  }
  __syncthreads();
  // scatter-add to 12 nodes: U[e]=e/6 (nodes 0..5), V[e]=6+e%6 (nodes 6..11)
  for (int idx = tid; idx < 12 * 64; idx += 256) {
    int j = idx >> 6, d = idx & 63;
    float a = 0.f;
    if (j < 6) { for (int i = 0; i < 6; i++) a += ef[j * 6 + i][d]; }
    else       { for (int i = 0; i < 6; i++) a += ef[i * 6 + (j - 6)][d]; }
    nin[j][d] = a;
  }
  __syncthreads();
  // e2n: relu(nin @ e2nw.T + e2nb) -> node[12][128]
  for (int idx = tid; idx < 12 * 128; idx += 256) {
    int j = idx >> 7, d = idx & 127;
    const float* wr = e2nw + d * 64;
    float a = e2nb[d];
    for (int k = 0; k < 64; k++) a += nin[j][k] * wr[k];
    nd[j][d] = fmaxf(a, 0.f);
  }
  __syncthreads();
  // attention scores: tanh(node @ a1w.T + a1b) @ a2w.T
  for (int idx = tid; idx < 12 * 64; idx += 256) {
    int j = idx >> 6, hh = idx & 63;
    const float* wr = a1w + hh * 128;
    float a = a1b[hh];
    for (int k = 0; k < 128; k++) a += nd[j][k] * wr[k];
    tmp[j][hh] = tanhf(a) * a2w[hh];
  }
  __syncthreads();
  if (tid < 12) {
    float a = 0.f;
    for (int h = 0; h < 64; h++) a += tmp[tid][h];
    scv[tid] = a;
  }
  __syncthreads();
  if (tid == 0) {
    float m = scv[0];
    for (int j = 1; j < 12; j++) m = fmaxf(m, scv[j]);
    float s = 0.f;
    for (int j = 0; j < 12; j++) { float z = expf(scv[j] - m); aw[j] = z; s += z; }
    float inv = 1.f / s;
    for (int j = 0; j < 12; j++) aw[j] *= inv;
    float rs = 0.f;
    for (int e = 0; e < 36; e++) { float r = aw[e / 6] * aw[6 + e % 6]; ea[e] = r; rs += r; }
    float inv2 = 1.f / (rs + 1e-8f);
    for (int e = 0; e < 36; e++) ea[e] *= inv2;
  }
  __syncthreads();
  if (tid < 36) out[96 + b * 36 + tid] = ea[tid];
  if (tid < 128) {
    float a = 0.f;
    for (int j = 0; j < 12; j++) a += nd[j][tid] * aw[j];
    g[tid] = a;
  }
  __syncthreads();
  if (tid < 3) {
    const float* wr = regw + tid * 128;
    float a = regb[tid];
    for (int k = 0; k < 128; k++) a += g[k] * wr[k];
    out[b * 3 + tid] = a;             // reg: [0, 24)
  }
  if (tid >= 64 && tid < 73) {
    int i = tid - 64;
    const float* wr = clsw + i * 128;
    float a = clsb[i];
    for (int k = 0; k < 128; k++) a += g[k] * wr[k];
    out[24 + b * 9 + i] = a;          // cls: [24, 96)
  }
}

extern "C" void kernel_launch(void* const* d_in, const int* in_sizes, int n_in,
                              void* d_out, int out_size, void* d_ws, size_t ws_size,
                              hipStream_t stream) {
  const float* x      = (const float*)d_in[0];
  const float* c1w    = (const float*)d_in[1];
  const float* c1b    = (const float*)d_in[2];
  const float* bn1s   = (const float*)d_in[3];
  const float* bn1b   = (const float*)d_in[4];
  const float* bn1m   = (const float*)d_in[5];
  const float* bn1v   = (const float*)d_in[6];
  const float* se1w1  = (const float*)d_in[7];
  const float* se1b1  = (const float*)d_in[8];
  const float* se1w2  = (const float*)d_in[9];
  const float* se1b2  = (const float*)d_in[10];
  const float* c2w    = (const float*)d_in[11];
  const float* c2b    = (const float*)d_in[12];
  const float* bn2s   = (const float*)d_in[13];
  const float* bn2b   = (const float*)d_in[14];
  const float* bn2m   = (const float*)d_in[15];
  const float* bn2v   = (const float*)d_in[16];
  const float* se2w1  = (const float*)d_in[17];
  const float* se2b1  = (const float*)d_in[18];
  const float* se2w2  = (const float*)d_in[19];
  const float* se2b2  = (const float*)d_in[20];
  const float* c3w    = (const float*)d_in[21];
  const float* c3b    = (const float*)d_in[22];
  const float* bn3s   = (const float*)d_in[23];
  const float* bn3b   = (const float*)d_in[24];
  const float* bn3m   = (const float*)d_in[25];
  const float* bn3v   = (const float*)d_in[26];
  const float* efw    = (const float*)d_in[27];
  const float* efb    = (const float*)d_in[28];
  const float* ew     = (const float*)d_in[29];
  const float* e2nw   = (const float*)d_in[30];
  const float* e2nb   = (const float*)d_in[31];
  const float* a1w    = (const float*)d_in[32];
  const float* a1b    = (const float*)d_in[33];
  const float* a2w    = (const float*)d_in[34];
  const float* clsw   = (const float*)d_in[35];
  const float* clsb   = (const float*)d_in[36];
  const float* regw   = (const float*)d_in[37];
  const float* regb   = (const float*)d_in[38];

  float* ws = (float*)d_ws;
  float* h1     = ws;                        // 288*16*16*512 = 37,748,736 f
  float* h2     = h1 + 37748736;             // 288*32*8*128  =  9,437,184 f
  float* sesum1 = h2 + 9437184;              // 4608 f
  float* s1     = sesum1 + 4608;             // 4608 f
  float* sesum2 = s1 + 4608;                 // 9216 f
  float* s2     = sesum2 + 9216;             // 9216 f
  float* h3     = s2 + 9216;                 // 18432 f

  hipMemsetAsync(sesum1, 0, 4608 * sizeof(float), stream);
  hipMemsetAsync(sesum2, 0, 9216 * sizeof(float), stream);

  k_conv1<<<288 * 32, 256, 0, stream>>>(x, c1w, c1b, bn1s, bn1b, bn1m, bn1v, h1, sesum1);
  k_se<<<5, 64, 0, stream>>>(sesum1, 16, 4, 1.f / 8192.f, se1w1, se1b1, se1w2, se1b2, s1);
  k_conv2<<<288 * 8, 256, 0, stream>>>(h1, c2w, c2b, bn2s, bn2b, bn2m, bn2v, s1, h2, sesum2);
  k_se<<<5, 64, 0, stream>>>(sesum2, 32, 8, 1.f / 1024.f, se2w1, se2b1, se2w2, se2b2, s2);
  k_conv3<<<288 * 2, 256, 0, stream>>>(h2, c3w, c3b, bn3s, bn3b, bn3m, bn3v, s2, h3);
  k_head<<<8, 256, 0, stream>>>(h3, efw, efb, ew, e2nw, e2nb, a1w, a1b, a2w,
                                clsw, clsb, regw, regb, (float*)d_out);
}